// Round 6
// baseline (838.518 us; speedup 1.0000x reference)
//
#include <hip/hip_runtime.h>

// TAMCaD_T fused attention-over-variables.
// q,k,v: (B=16, G=32, H=32, S=4096) fp32, s contiguous.
// Per (b,s): logits[g][f] = scale * sum_d q[g,d]k[f,d]; attn = softmax_f; x[g,d] = sum_f attn*v[f,d].
// Outputs (concat fp32): x (B,G*H,S) | attentions (B,G,G,S) | logits (B,G,G,S).
//
// Round-4 structure (resubmitted; two infra failures, kernel never executed):
//  - TS=32, 1024 threads, thread=(g,s): every global access is a full 128-B line
//    (round 3 showed 1.68x write amp from 64-B half-line writes + register spills).
//  - One 64-KB LDS buffer, k staged then v staged (3 barriers) -> 2 blocks/CU
//    = 32 waves/CU (100% occupancy) at VGPR<=64.
//  - QK and PV each split into two d-half passes so live registers stay ~58
//    (no spill): pass A uses LDS chunks 0,1 (d 0..15), pass B chunks 2,3.
//  - Softmax fully thread-local; attn kept in registers for PV.

constexpr int S_LEN = 4096;
constexpr int GG = 32;   // groups (q and kv)
constexpr int HH = 32;   // hidden dim (dk), n_heads = 1
constexpr int TS = 32;   // timesteps per block -> 128-B global segments
constexpr float SCALE = 0.17677669529663687f;  // 32^-0.5

__device__ __forceinline__ unsigned bf16pack(float a, float b) {
    // round-to-nearest-even bf16 pair in a u32 (lo = a, hi = b)
    unsigned ua = __float_as_uint(a);
    unsigned ub = __float_as_uint(b);
    ua = (ua + 0x7fffu + ((ua >> 16) & 1u)) >> 16;
    ub = (ub + 0x7fffu + ((ub >> 16) & 1u)) >> 16;
    return ua | (ub << 16);
}

__global__ __launch_bounds__(1024, 8) void tamcad_fused(
    const float* __restrict__ q, const float* __restrict__ k,
    const float* __restrict__ v, float* __restrict__ x_out,
    float* __restrict__ attn_out, float* __restrict__ logit_out)
{
    // u32 index for element (f, d=2*dp+h, s): f*512 + s*16 + slot(dp,s)
    //   slot(dp,s) = (((dp>>2) ^ ((s>>1)&3)) << 2) | (dp&3)
    // One buffer, holds k during QK, then v during PV.
    __shared__ __align__(16) unsigned lds[GG * TS * 16];  // 16384 u32 = 64 KB

    // XCD-bijective swizzle (nwg = 2048, divisible by 8)
    const int nwg = gridDim.x;
    const int cpx = nwg >> 3;
    const int raw = blockIdx.x;
    const int logical = (raw & 7) * cpx + (raw >> 3);
    const int b  = logical >> 7;       // / (S/TS = 128)
    const int st = logical & 127;
    const int s0 = st * TS;

    const int tid = threadIdx.x;
    const int g = tid >> 5;            // 0..31
    const int s = tid & 31;            // 0..31

    // staging role: one (f, d-pair, s-half) unit per thread
    const int fst = tid >> 5;          // 0..31
    const int dp  = (tid >> 1) & 15;   // 0..15
    const int sh  = tid & 1;           // 0..1
    const int dpl = dp & 3;
    const int dph = dp & 12;           // (dp>>2)<<2

    const int baseB = b * (GG * HH);
    const float* qb = q + (size_t)baseB * S_LEN + s0;
    const float* kb = k + (size_t)baseB * S_LEN + s0;
    const float* vb = v + (size_t)baseB * S_LEN + s0;

// Stage one array (k or v) into the shared 64-KB buffer as bf16 d-pairs.
// Per thread: 2 rows x 16 s (64 B per row, lane-pairs cover the 128-B line).
// Paired ds writes (+0, +64 B, same bank slot) -> fuses to ds_write2_b32.
#define STAGE(SRC) do { \
    const float* r0_ = (SRC) + (size_t)(fst * HH + 2 * dp) * S_LEN + sh * 16; \
    const float* r1_ = r0_ + S_LEN; \
    unsigned* const lb_ = &lds[fst * 512 + dpl]; \
    _Pragma("unroll") \
    for (int sq_ = 0; sq_ < 4; ++sq_) { \
        const float4 a4_ = *reinterpret_cast<const float4*>(r0_ + sq_ * 4); \
        const float4 b4_ = *reinterpret_cast<const float4*>(r1_ + sq_ * 4); \
        const float al_[4] = {a4_.x, a4_.y, a4_.z, a4_.w}; \
        const float bl_[4] = {b4_.x, b4_.y, b4_.z, b4_.w}; \
        _Pragma("unroll") \
        for (int e_ = 0; e_ < 4; e_ += 2) { \
            const int s_  = sh * 16 + sq_ * 4 + e_; \
            const int xs_ = (s_ >> 1) & 3; \
            unsigned* wp_ = lb_ + s_ * 16 + (dph ^ (xs_ << 2)); \
            wp_[0]  = bf16pack(al_[e_],     bl_[e_]); \
            wp_[16] = bf16pack(al_[e_ + 1], bl_[e_ + 1]); \
        } \
    } \
} while (0)

    // ---- stage K; load q d-half A ----
    STAGE(kb);
    float qr[16];
    #pragma unroll
    for (int d = 0; d < 16; ++d)
        qr[d] = qb[(size_t)(g * HH + d) * S_LEN + s];
    __syncthreads();

    // hot-loop read pointers: chunk c lives at group (c ^ xs)
    const int xs = (s >> 1) & 3;
    const unsigned* const rp0 = &lds[s * 16 + ((0 ^ xs) << 2)];
    const unsigned* const rp1 = &lds[s * 16 + ((1 ^ xs) << 2)];
    const unsigned* const rp2 = &lds[s * 16 + ((2 ^ xs) << 2)];
    const unsigned* const rp3 = &lds[s * 16 + ((3 ^ xs) << 2)];

#define QKW(u, d0) { \
        const float klo_ = __uint_as_float((u) << 16); \
        const float khi_ = __uint_as_float((u) & 0xffff0000u); \
        a0 = fmaf(qr[d0], klo_, a0); \
        a1 = fmaf(qr[(d0) + 1], khi_, a1); }

    // ---- QK^T pass A: d 0..15 (chunks 0,1) ----
    float l[32];
    #pragma unroll
    for (int f = 0; f < 32; ++f) {
        const uint4 c0 = *reinterpret_cast<const uint4*>(rp0 + f * 512);
        const uint4 c1 = *reinterpret_cast<const uint4*>(rp1 + f * 512);
        float a0 = 0.f, a1 = 0.f;
        QKW(c0.x,  0) QKW(c0.y,  2) QKW(c0.z,  4) QKW(c0.w,  6)
        QKW(c1.x,  8) QKW(c1.y, 10) QKW(c1.z, 12) QKW(c1.w, 14)
        l[f] = a0 + a1;
    }
    // ---- q d-half B, QK pass B: d 16..31 (chunks 2,3); scale + logit store ----
    #pragma unroll
    for (int d = 0; d < 16; ++d)
        qr[d] = qb[(size_t)(g * HH + 16 + d) * S_LEN + s];
    #pragma unroll
    for (int f = 0; f < 32; ++f) {
        const uint4 c2 = *reinterpret_cast<const uint4*>(rp2 + f * 512);
        const uint4 c3 = *reinterpret_cast<const uint4*>(rp3 + f * 512);
        float a0 = 0.f, a1 = 0.f;
        QKW(c2.x,  0) QKW(c2.y,  2) QKW(c2.z,  4) QKW(c2.w,  6)
        QKW(c3.x,  8) QKW(c3.y, 10) QKW(c3.z, 12) QKW(c3.w, 14)
        l[f] = (l[f] + a0 + a1) * SCALE;
        logit_out[(size_t)(baseB + g * GG + f) * S_LEN + s0 + s] = l[f];
    }
#undef QKW

    // ---- softmax over f, fully thread-local ----
    {
        float tm[16];
        #pragma unroll
        for (int i = 0; i < 16; ++i) tm[i] = fmaxf(l[2 * i], l[2 * i + 1]);
        #pragma unroll
        for (int i = 0; i < 8; ++i) tm[i] = fmaxf(tm[i], tm[i + 8]);
        #pragma unroll
        for (int i = 0; i < 4; ++i) tm[i] = fmaxf(tm[i], tm[i + 4]);
        const float m = fmaxf(fmaxf(tm[0], tm[1]), fmaxf(tm[2], tm[3]));
        float ts4[4] = {0.f, 0.f, 0.f, 0.f};
        #pragma unroll
        for (int f = 0; f < 32; ++f) {
            l[f] = __expf(l[f] - m);
            ts4[f & 3] += l[f];
        }
        const float sum = (ts4[0] + ts4[1]) + (ts4[2] + ts4[3]);
        const float inv = __builtin_amdgcn_rcpf(sum);
        #pragma unroll
        for (int f = 0; f < 32; ++f) {
            l[f] *= inv;
            attn_out[(size_t)(baseB + g * GG + f) * S_LEN + s0 + s] = l[f];
        }
    }

    // ---- swap LDS buffer to v ----
    __syncthreads();   // all k reads done
    STAGE(vb);
    __syncthreads();

#define PVW(u, d0) { \
        const float vlo_ = __uint_as_float((u) << 16); \
        const float vhi_ = __uint_as_float((u) & 0xffff0000u); \
        xa[d0] = fmaf(av, vlo_, xa[d0]); \
        xa[(d0) + 1] = fmaf(av, vhi_, xa[(d0) + 1]); }

    // ---- PV pass A: d 0..15 (chunks 0,1) ----
    {
        float xa[16];
        #pragma unroll
        for (int d = 0; d < 16; ++d) xa[d] = 0.f;
        #pragma unroll
        for (int f = 0; f < 32; ++f) {
            const float av = l[f];
            const uint4 c0 = *reinterpret_cast<const uint4*>(rp0 + f * 512);
            const uint4 c1 = *reinterpret_cast<const uint4*>(rp1 + f * 512);
            PVW(c0.x,  0) PVW(c0.y,  2) PVW(c0.z,  4) PVW(c0.w,  6)
            PVW(c1.x,  8) PVW(c1.y, 10) PVW(c1.z, 12) PVW(c1.w, 14)
        }
        #pragma unroll
        for (int d = 0; d < 16; ++d)
            x_out[(size_t)(baseB + g * HH + d) * S_LEN + s0 + s] = xa[d];
    }
    // ---- PV pass B: d 16..31 (chunks 2,3) ----
    {
        float xa[16];
        #pragma unroll
        for (int d = 0; d < 16; ++d) xa[d] = 0.f;
        #pragma unroll
        for (int f = 0; f < 32; ++f) {
            const float av = l[f];
            const uint4 c2 = *reinterpret_cast<const uint4*>(rp2 + f * 512);
            const uint4 c3 = *reinterpret_cast<const uint4*>(rp3 + f * 512);
            PVW(c2.x,  0) PVW(c2.y,  2) PVW(c2.z,  4) PVW(c2.w,  6)
            PVW(c3.x,  8) PVW(c3.y, 10) PVW(c3.z, 12) PVW(c3.w, 14)
        }
        #pragma unroll
        for (int d = 0; d < 16; ++d)
            x_out[(size_t)(baseB + g * HH + 16 + d) * S_LEN + s0 + s] = xa[d];
    }
#undef PVW
#undef STAGE
}

extern "C" void kernel_launch(void* const* d_in, const int* in_sizes, int n_in,
                              void* d_out, int out_size, void* d_ws, size_t ws_size,
                              hipStream_t stream) {
    const float* q = (const float*)d_in[0];
    const float* k = (const float*)d_in[1];
    const float* v = (const float*)d_in[2];
    float* out = (float*)d_out;
    const int n = in_sizes[0];                  // B*G*H*S = 67108864
    const int B = n / (GG * HH * S_LEN);        // 16
    float* x_out     = out;
    float* attn_out  = out + (size_t)n;
    float* logit_out = out + (size_t)2 * n;
    const int nwg = B * (S_LEN / TS);           // 2048
    tamcad_fused<<<dim3(nwg), dim3(1024), 0, stream>>>(q, k, v, x_out, attn_out, logit_out);
}